// Round 2
// baseline (2060.199 us; speedup 1.0000x reference)
//
#include <hip/hip_runtime.h>
#include <stdint.h>

typedef short bf16x4 __attribute__((ext_vector_type(4)));
typedef short bf16x8 __attribute__((ext_vector_type(8)));
typedef float f32x4  __attribute__((ext_vector_type(4)));

__device__ __forceinline__ short f2bf(float f) {
    uint32_t u = __builtin_bit_cast(uint32_t, f);
    u += 0x7FFFu + ((u >> 16) & 1u);   // round-to-nearest-even
    return (short)(u >> 16);
}

// Wt[t][oc][ic] = bf16(W[t][ic][oc]);  t = dy*3+dx
__global__ void wt_kernel(const float* __restrict__ W, short* __restrict__ Wt) {
    int idx = blockIdx.x * 256 + threadIdx.x;
    if (idx >= 9 * 256 * 64) return;
    int t   = idx >> 14;
    int rem = idx & 16383;
    int oc  = rem >> 6;
    int ic  = rem & 63;
    Wt[idx] = f2bf(W[(t * 64 + ic) * 256 + oc]);
}

#define AS_SHORTS (6 * 66 * 72)   // 28512 shorts = 57,024 B
#define BS_SHORTS (9 * 64 * 72)   // 41472 shorts = 82,944 B

// Implicit-GEMM conv3x3 + bias + pixel_shuffle(R=2), bf16 MFMA.
// Block: 512 thr = 8 waves = 4 M-subtiles (64 rows each) x 2 K-halves.
// Tile: M=256 (4 h-rows x 64 w), N=64 oc, K=576. Stage A+B ONCE, then
// barrier-free 144-MFMA chain per wave; cross-K reduction via LDS scratch.
__global__ __launch_bounds__(512) void conv_ps_kernel(
    const float* __restrict__ x, const short* __restrict__ Wt,
    const float* __restrict__ bias, float* __restrict__ out)
{
    __shared__ short smem[AS_SHORTS + BS_SHORTS];   // 139,968 B
    short* As = smem;
    short* Bs = smem + AS_SHORTS;

    const int tid   = threadIdx.x;
    const int lane  = tid & 63;
    const int wv    = tid >> 6;
    const int pm    = wv & 3;     // M-subtile index (output h_local), 64 rows
    const int kh    = wv >> 2;    // K-half (0/1): ic 0..31 vs 32..63 of every tap
    const int row_l = lane & 15;
    const int grp   = lane >> 4;

    // XCD-aware logical block id (nwg = 9216, divisible by 8)
    const int raw = blockIdx.x;
    const int lb  = (raw & 7) * (9216 / 8) + (raw >> 3);
    const int ocb = lb & 3;            // innermost: oc-siblings share an XCD/L2
    const int wt  = (lb >> 2) % 3;
    const int hq  = (lb / 12) % 48;
    const int n   = lb / 576;
    const int h0  = hq * 4;
    const int w0  = wt * 64;

    // ---- stage A: x[n, h0-1 .. h0+4, w0-1 .. w0+64, 0:64] -> bf16 ----
    for (int i = tid; i < 6336; i += 512) {       // 6*66*16 f32x4 chunks
        int r   = i / 1056;
        int j   = i - r * 1056;
        int pos = j >> 4;
        int c4  = (j & 15) << 2;
        int hy  = h0 + r - 1;
        int wg  = w0 - 1 + pos;
        f32x4 v = (f32x4)0.0f;
        if ((unsigned)hy < 192u && (unsigned)wg < 192u)
            v = *(const f32x4*)(x + (((size_t)n * 192 + hy) * 192 + wg) * 64 + c4);
        bf16x4 s;
        s[0] = f2bf(v[0]); s[1] = f2bf(v[1]); s[2] = f2bf(v[2]); s[3] = f2bf(v[3]);
        *(bf16x4*)&As[(r * 66 + pos) * 72 + c4] = s;
    }
    // ---- stage B: all 9 taps, this block's 64 oc ----
    {
        const short* wsrc = Wt + ocb * 4096;      // [t][oc][ic], t-stride 16384
        for (int i = tid; i < 4608; i += 512) {   // 9*64*8 b128 chunks
            int t = i >> 9;
            int r = i & 511;                      // oc_l*8 + chunk8
            bf16x8 v = *(const bf16x8*)(wsrc + t * 16384 + r * 8);
            *(bf16x8*)&Bs[(t * 64 + (r >> 3)) * 72 + (r & 7) * 8] = v;
        }
    }
    __syncthreads();

    f32x4 acc[4][4];
    #pragma unroll
    for (int i = 0; i < 4; ++i)
        #pragma unroll
        for (int j = 0; j < 4; ++j)
            acc[i][j] = (f32x4)0.0f;

    const int koff = kh * 32 + grp * 8;   // this wave's 32-ic half of each tap

    #pragma unroll
    for (int t = 0; t < 9; ++t) {
        const int dy = t / 3, dx = t % 3;
        bf16x8 af[4], bfr[4];
        #pragma unroll
        for (int mt = 0; mt < 4; ++mt)
            af[mt] = *(const bf16x8*)&As[((pm + dy) * 66 + mt * 16 + row_l + dx) * 72 + koff];
        #pragma unroll
        for (int nt = 0; nt < 4; ++nt)
            bfr[nt] = *(const bf16x8*)&Bs[(t * 64 + nt * 16 + row_l) * 72 + koff];
        #pragma unroll
        for (int mt = 0; mt < 4; ++mt)
            #pragma unroll
            for (int nt = 0; nt < 4; ++nt)
                acc[mt][nt] = __builtin_amdgcn_mfma_f32_16x16x32_bf16(
                    af[mt], bfr[nt], acc[mt][nt], 0, 0, 0);
    }

    // ---- cross-K reduction: wave kh keeps nt in {2kh, 2kh+1}, sends the others ----
    __syncthreads();                      // compute done; smem reusable
    f32x4* scr = (f32x4*)smem;            // 4 pm * 2 kh * 8 frag * 64 lane = 64 KB
    #pragma unroll
    for (int mt = 0; mt < 4; ++mt)
        #pragma unroll
        for (int ntl = 0; ntl < 2; ++ntl)
            scr[(((pm * 2 + kh) * 8) + mt * 2 + ntl) * 64 + lane] =
                acc[mt][2 * (1 - kh) + ntl];
    __syncthreads();
    #pragma unroll
    for (int mt = 0; mt < 4; ++mt)
        #pragma unroll
        for (int ntl = 0; ntl < 2; ++ntl)
            acc[mt][2 * kh + ntl] += scr[(((pm * 2 + (1 - kh)) * 8) + mt * 2 + ntl) * 64 + lane];

    // ---- epilogue: bias + pixel shuffle, this wave writes its kept 2 nt ----
    const int h = h0 + pm;
    #pragma unroll
    for (int ntl = 0; ntl < 2; ++ntl) {
        const int nt   = 2 * kh + ntl;
        const int oc_l = nt * 16 + row_l;
        const int oc   = ocb * 64 + oc_l;
        const float bv = bias[oc];
        const int q  = oc_l & 1;
        const int pp = (oc_l >> 1) & 1;
        const int kb = ocb * 16 + (oc_l >> 2);
        const long rowb = ((long)(n * 384 + 2 * h + q)) * 384;
        #pragma unroll
        for (int mt = 0; mt < 4; ++mt) {
            #pragma unroll
            for (int j = 0; j < 4; ++j) {
                int w = w0 + mt * 16 + grp * 4 + j;
                out[(rowb + 2 * w + pp) * 64 + kb] = acc[mt][nt][j] + bv;
            }
        }
    }
}

extern "C" void kernel_launch(void* const* d_in, const int* in_sizes, int n_in,
                              void* d_out, int out_size, void* d_ws, size_t ws_size,
                              hipStream_t stream) {
    const float* x = (const float*)d_in[0];
    const float* W = (const float*)d_in[1];
    const float* b = (const float*)d_in[2];
    float* out = (float*)d_out;
    short* Wt  = (short*)d_ws;   // 9*256*64 bf16 = 294,912 B

    hipLaunchKernelGGL(wt_kernel, dim3(576), dim3(256), 0, stream, W, Wt);
    hipLaunchKernelGGL(conv_ps_kernel, dim3(9216), dim3(512), 0, stream, x, Wt, b, out);
}

// Round 4
// 401.207 us; speedup vs baseline: 5.1350x; 5.1350x over previous
//
#include <hip/hip_runtime.h>
#include <stdint.h>

typedef short bf16x8 __attribute__((ext_vector_type(8)));
typedef float f32x4  __attribute__((ext_vector_type(4)));

__device__ __forceinline__ uint32_t bfbits(float f) {
    uint32_t u = __builtin_bit_cast(uint32_t, f);
    u += 0x7FFFu + ((u >> 16) & 1u);   // round-to-nearest-even
    return u >> 16;
}
__device__ __forceinline__ uint32_t pk2(float a, float b) {
    return bfbits(a) | (bfbits(b) << 16);
}

// Wt[t][c][j][ic] = bf16(W[dy][dx][ic][j*4+c]); block c owns oc = j*4+c (one PS quadrant).
__global__ void wt_kernel(const float* __restrict__ W, short* __restrict__ Wt) {
    int idx = blockIdx.x * 256 + threadIdx.x;      // 9*4*64*64 = 147456
    if (idx >= 147456) return;
    int t  = idx >> 14;
    int r  = idx & 16383;
    int c  = r >> 12;
    int j  = (r >> 6) & 63;
    int ic = r & 63;
    Wt[idx] = (short)bfbits(W[(t * 64 + ic) * 256 + j * 4 + c]);
}

#define NT 6
#define A_SLOT 4224              // shorts per h-row slot: 66 wpos * 64 ic
#define A_SH   (10 * A_SLOT)     // 42240 shorts = 84,480 B (10-row ring)
#define B_SH   (9 * 64 * 64)     // 36864 shorts = 73,728 B

// Implicit-GEMM conv3x3 + bias + pixel_shuffle quadrant, bf16 MFMA.
// Block: 512 thr = 8 waves, wave = 1 h-row x 64 w x 64 j, full K=576, no reduction.
// B resident (once), A ring-buffered with register-staged prefetch of next tile.
__global__ __launch_bounds__(512, 2) void conv_ps_kernel(
    const float* __restrict__ x, const short* __restrict__ Wt,
    const float* __restrict__ bias, float* __restrict__ out)
{
    __shared__ short smem[A_SH + B_SH];   // 158,208 B
    short* As = smem;
    short* Bs = smem + A_SH;

    const int tid   = threadIdx.x;
    const int lane  = tid & 63;
    const int wv    = tid >> 6;       // pm: which of 8 h-rows in the tile
    const int row_l = lane & 15;
    const int grp   = lane >> 4;
    const int b7    = row_l & 7;

    // XCD-aware bijective swizzle (nwg = 768 % 8 == 0); c innermost -> the 4
    // quadrant-siblings sharing an x-tile land on the same XCD's L2.
    const int raw = blockIdx.x;
    const int lb  = (raw & 7) * 96 + (raw >> 3);
    const int c   = lb & 3;
    const int wt  = (lb >> 2) % 3;
    const int hg  = (lb / 12) & 3;
    const int n   = lb / 48;
    const int w0  = wt * 64;
    const int hbase = hg * 48;
    const int q = c & 1, p = (c >> 1) & 1;

    // ---- prologue: B once (write-side XOR swizzle on 16B slots) ----
    {
        const short* wsrc = Wt + c * 4096;         // [t][c][j][ic], t-stride 16384
        for (int k = 0; k < 9; ++k) {
            int cid = tid + k * 512;               // 0..4607
            int t = cid >> 9, j = (cid >> 3) & 63, s = cid & 7;
            bf16x8 v = *(const bf16x8*)(wsrc + t * 16384 + j * 64 + s * 8);
            *(bf16x8*)&Bs[t * 4096 + j * 64 + ((s ^ (j & 7)) << 3)] = v;
        }
    }
    // ---- prologue: A ring, rows hbase-1 .. hbase+8 (10 rows) ----
    for (int k = 0; k < 21; ++k) {
        int cid = tid + k * 512;                   // 0..10559
        if (cid < 10560) {
            int rl   = cid / 1056;
            int rem  = cid - rl * 1056;
            int wpos = rem >> 4;
            int c4   = rem & 15;
            int r_abs = hbase - 1 + rl;
            int wg    = w0 - 1 + wpos;
            f32x4 v = {0.f, 0.f, 0.f, 0.f};
            if ((unsigned)r_abs < 192u && (unsigned)wg < 192u)
                v = *(const f32x4*)(x + (((size_t)n * 192 + r_abs) * 192 + wg) * 64 + c4 * 4);
            int slot = (hbase + rl) % 10;
            uint32_t lo = pk2(v[0], v[1]), hi = pk2(v[2], v[3]);
            uint32_t* d = (uint32_t*)&As[slot * A_SLOT + wpos * 64 +
                                         (((c4 >> 1) ^ (wpos & 7)) << 3) + (c4 & 1) * 4];
            d[0] = lo; d[1] = hi;
        }
    }
    __syncthreads();

    float bv[4];
    #pragma unroll
    for (int nt = 0; nt < 4; ++nt) bv[nt] = bias[(nt * 16 + row_l) * 4 + c];

    for (int it = 0; it < NT; ++it) {
        const int h0 = hbase + it * 8;

        // 1. issue next tile's 8 fresh rows (h0+9 .. h0+16) into registers
        f32x4 stg[17];
        if (it < NT - 1) {
            #pragma unroll
            for (int k = 0; k < 17; ++k) {
                int cid = tid + k * 512;           // 0..8447 valid
                f32x4 v = {0.f, 0.f, 0.f, 0.f};
                if (cid < 8448) {
                    int rl   = cid / 1056;
                    int rem  = cid - rl * 1056;
                    int wpos = rem >> 4;
                    int c4   = rem & 15;
                    int r_abs = h0 + 9 + rl;
                    int wg    = w0 - 1 + wpos;
                    if (r_abs < 192 && (unsigned)wg < 192u)
                        v = *(const f32x4*)(x + (((size_t)n * 192 + r_abs) * 192 + wg) * 64 + c4 * 4);
                }
                stg[k] = v;
            }
        }

        // 2. compute: full K=576 for this wave's 64x64 tile, barrier-free
        f32x4 acc[4][4];
        #pragma unroll
        for (int i = 0; i < 4; ++i)
            #pragma unroll
            for (int j = 0; j < 4; ++j) acc[i][j] = (f32x4)0.0f;

        int sl[3];
        #pragma unroll
        for (int dy = 0; dy < 3; ++dy) sl[dy] = (h0 + wv + dy) % 10;

        #pragma unroll
        for (int dy = 0; dy < 3; ++dy) {
            #pragma unroll
            for (int dx = 0; dx < 3; ++dx) {
                const int t  = dy * 3 + dx;
                const int rd = row_l + dx;
                const int a7 = rd & 7;
                const int aB = sl[dy] * A_SLOT + rd * 64;
                const int bB = t * 4096 + row_l * 64;
                #pragma unroll
                for (int ks = 0; ks < 2; ++ks) {
                    const int kg = ks * 4 + grp;
                    const short* ap = &As[aB + ((kg ^ a7) << 3)];
                    const short* bp = &Bs[bB + ((kg ^ b7) << 3)];
                    bf16x8 af[4], bfr[4];
                    #pragma unroll
                    for (int mt = 0; mt < 4; ++mt) af[mt]  = *(const bf16x8*)(ap + mt * 1024);
                    #pragma unroll
                    for (int nt = 0; nt < 4; ++nt) bfr[nt] = *(const bf16x8*)(bp + nt * 1024);
                    #pragma unroll
                    for (int mt = 0; mt < 4; ++mt)
                        #pragma unroll
                        for (int nt = 0; nt < 4; ++nt)
                            acc[mt][nt] = __builtin_amdgcn_mfma_f32_16x16x32_bf16(
                                af[mt], bfr[nt], acc[mt][nt], 0, 0, 0);
                }
            }
        }

        // 3. epilogue: bias + store. Quadrant (q,p) fixed per block -> full k-rows.
        {
            const int h = h0 + wv;
            const long rowb = ((long)(n * 384 + 2 * h + q)) * 384;
            #pragma unroll
            for (int mt = 0; mt < 4; ++mt) {
                float* po = out + ((rowb + 2 * (w0 + mt * 16 + grp * 4) + p) * 64 + row_l);
                #pragma unroll
                for (int nt = 0; nt < 4; ++nt)
                    #pragma unroll
                    for (int jv = 0; jv < 4; ++jv)
                        po[jv * 128 + nt * 16] = acc[mt][nt][jv] + bv[nt];
            }
        }

        __syncthreads();   // all waves done reading the ring slots being replaced

        // 4. convert + ds_write staged rows into ring slots (h0+10+rl) % 10
        if (it < NT - 1) {
            #pragma unroll
            for (int k = 0; k < 17; ++k) {
                int cid = tid + k * 512;
                if (cid < 8448) {
                    int rl   = cid / 1056;
                    int rem  = cid - rl * 1056;
                    int wpos = rem >> 4;
                    int c4   = rem & 15;
                    int slot = (h0 + 10 + rl) % 10;
                    uint32_t lo = pk2(stg[k][0], stg[k][1]), hi = pk2(stg[k][2], stg[k][3]);
                    uint32_t* d = (uint32_t*)&As[slot * A_SLOT + wpos * 64 +
                                                 (((c4 >> 1) ^ (wpos & 7)) << 3) + (c4 & 1) * 4];
                    d[0] = lo; d[1] = hi;
                }
            }
        }
        __syncthreads();   // new rows visible before next tile's reads
    }
}

extern "C" void kernel_launch(void* const* d_in, const int* in_sizes, int n_in,
                              void* d_out, int out_size, void* d_ws, size_t ws_size,
                              hipStream_t stream) {
    const float* x = (const float*)d_in[0];
    const float* W = (const float*)d_in[1];
    const float* b = (const float*)d_in[2];
    float* out = (float*)d_out;
    short* Wt  = (short*)d_ws;   // 9*4*64*64 bf16 = 294,912 B

    hipLaunchKernelGGL(wt_kernel, dim3(576), dim3(256), 0, stream, W, Wt);
    hipLaunchKernelGGL(conv_ps_kernel, dim3(768), dim3(512), 0, stream, x, Wt, b, out);
}